// Round 1
// baseline (414.136 us; speedup 1.0000x reference)
//
#include <hip/hip_runtime.h>
#include <hip/hip_bf16.h>
#include <math.h>

#define NTOK 4096
#define CH 512
#define CQD 64
#define NBATCH 4

typedef __bf16 bf16x8 __attribute__((ext_vector_type(8)));
typedef float f32x4 __attribute__((ext_vector_type(4)));
typedef unsigned int u32x4 __attribute__((ext_vector_type(4)));
typedef unsigned short u16x4 __attribute__((ext_vector_type(4)));

__device__ __forceinline__ unsigned short f2bf(float f) {
  unsigned int u = __builtin_bit_cast(unsigned int, f);
  unsigned int r = (u + 0x7FFFu + ((u >> 16) & 1u)) >> 16;
  return (unsigned short)r;
}

__device__ __forceinline__ bf16x8 load_frag(const unsigned short* p) {
  u32x4 v = *reinterpret_cast<const u32x4*>(p);
  return __builtin_bit_cast(bf16x8, v);
}

// ---- K0a: transpose + convert x -> xT bf16 (B, N, 1024): [0..511]=xs, [512..1023]=xt
__global__ void k_transpose(const float* __restrict__ xs, const float* __restrict__ xt,
                            unsigned short* __restrict__ xT) {
  __shared__ unsigned short lds[64][66];
  int b = blockIdx.z;
  int n0 = blockIdx.x * 64;
  int c0 = blockIdx.y * 64;  // 0..1023
  const float* src = (c0 < CH) ? xs : xt;
  int cs0 = (c0 < CH) ? c0 : c0 - CH;
  int tid = threadIdx.x;
  int nn = tid & 63, cg = tid >> 6;
  const float* base = src + ((size_t)b * CH + cs0) * NTOK + n0;
  for (int cc = cg; cc < 64; cc += 4)
    lds[cc][nn] = f2bf(base[(size_t)cc * NTOK + nn]);
  __syncthreads();
  int cw = tid & 63, ng = tid >> 6;
  unsigned short* dst = xT + ((size_t)b * NTOK + n0) * 1024 + c0 + cw;
  for (int n2 = ng; n2 < 64; n2 += 4)
    dst[(size_t)n2 * 1024] = lds[cw][n2];
}

// ---- K0b: weights f32 -> bf16 (Wq, Wk, Wv = [Wvs | Wvt])
__global__ void k_weights(const float* __restrict__ Wq, const float* __restrict__ Wk,
                          const float* __restrict__ Wvs, const float* __restrict__ Wvt,
                          unsigned short* __restrict__ wq, unsigned short* __restrict__ wk,
                          unsigned short* __restrict__ wv) {
  int t = blockIdx.x * 256 + threadIdx.x;
  if (t < 32768) {
    wq[t] = f2bf(Wq[t]);
  } else if (t < 65536) {
    int j = t - 32768;
    wk[j] = f2bf(Wk[j]);
  } else {
    int j = t - 65536;
    if (j < 512 * 1024) {
      int c = j >> 10, k = j & 1023;
      float v = (k < 512) ? Wvs[c * 512 + k] : Wvt[c * 512 + (k - 512)];
      wv[j] = f2bf(v);
    }
  }
}

// ---- K1: projection GEMM. D[n][m] = sum_k xT[b][n][koff+k] * W[m][k] (+bias)
// mode 0: out[b][n][m] (N x 64) scalar bf16 stores (for Q, Kt)
// mode 1: out[b][m][n] (C x N) packed 4-wide bf16 stores (for V)
__global__ void __launch_bounds__(256)
k_proj(const unsigned short* __restrict__ xT, const unsigned short* __restrict__ W,
       const float* __restrict__ bias1, const float* __restrict__ bias2,
       unsigned short* __restrict__ out, int Kdim, int koff, int mode) {
  int b = blockIdx.z;
  int n0 = blockIdx.x * 256;
  int m0 = blockIdx.y * 64;
  int tid = threadIdx.x;
  int w = tid >> 6, l = tid & 63;
  int fr = l & 15, fk = l >> 4;
  f32x4 acc[4][4] = {};  // [nstrip][mfrag]
  const unsigned short* xbase =
      xT + ((size_t)b * NTOK + n0 + w * 64 + fr) * 1024 + koff + fk * 8;
  const unsigned short* wbase = W + ((size_t)(m0 + fr)) * Kdim + fk * 8;
  for (int k = 0; k < Kdim; k += 32) {
    bf16x8 a[4], bb[4];
#pragma unroll
    for (int ns = 0; ns < 4; ns++) a[ns] = load_frag(xbase + (size_t)ns * 16 * 1024 + k);
#pragma unroll
    for (int mf = 0; mf < 4; mf++) bb[mf] = load_frag(wbase + (size_t)mf * 16 * Kdim + k);
#pragma unroll
    for (int ns = 0; ns < 4; ns++)
#pragma unroll
      for (int mf = 0; mf < 4; mf++)
        acc[ns][mf] = __builtin_amdgcn_mfma_f32_16x16x32_bf16(a[ns], bb[mf], acc[ns][mf], 0, 0, 0);
  }
  if (mode == 0) {
#pragma unroll
    for (int ns = 0; ns < 4; ns++)
#pragma unroll
      for (int mf = 0; mf < 4; mf++) {
        int m = m0 + mf * 16 + fr;
        float bv = bias1[m];
        int nb = n0 + w * 64 + ns * 16 + fk * 4;
#pragma unroll
        for (int r = 0; r < 4; r++)
          out[((size_t)b * NTOK + nb + r) * CQD + m] = f2bf(acc[ns][mf][r] + bv);
      }
  } else {
#pragma unroll
    for (int ns = 0; ns < 4; ns++)
#pragma unroll
      for (int mf = 0; mf < 4; mf++) {
        int c = m0 + mf * 16 + fr;
        float bv = bias1[c] + bias2[c];
        int nb = n0 + w * 64 + ns * 16 + fk * 4;
        u16x4 pk;
#pragma unroll
        for (int r = 0; r < 4; r++) pk[r] = f2bf(acc[ns][mf][r] + bv);
        *reinterpret_cast<u16x4*>(out + ((size_t)b * CH + c) * NTOK + nb) = pk;
      }
  }
}

// ---- K2: softmax stats. m[b][i] = max_j e, rl[b][i] = 1/sum_j exp(e-m), e = 0.125*S
__global__ void __launch_bounds__(256)
k_stats(const unsigned short* __restrict__ Q, const unsigned short* __restrict__ Kt,
        float* __restrict__ mArr, float* __restrict__ rlArr) {
  int b = blockIdx.y;
  int tid = threadIdx.x;
  int w = tid >> 6, l = tid & 63, fr = l & 15, fk = l >> 4;
  int i0 = blockIdx.x * 64 + w * 16;
  const unsigned short* qb = Q + ((size_t)b * NTOK + i0 + fr) * CQD + fk * 8;
  bf16x8 q0 = load_frag(qb), q1 = load_frag(qb + 32);
  const unsigned short* kb = Kt + ((size_t)b * NTOK + fr) * CQD + fk * 8;
  float mr[4] = {-INFINITY, -INFINITY, -INFINITY, -INFINITY};
  float lr[4] = {0.f, 0.f, 0.f, 0.f};
  for (int j = 0; j < NTOK; j += 16) {
    bf16x8 k0 = load_frag(kb + (size_t)j * CQD);
    bf16x8 k1 = load_frag(kb + (size_t)j * CQD + 32);
    f32x4 s = {};
    s = __builtin_amdgcn_mfma_f32_16x16x32_bf16(q0, k0, s, 0, 0, 0);
    s = __builtin_amdgcn_mfma_f32_16x16x32_bf16(q1, k1, s, 0, 0, 0);
#pragma unroll
    for (int r = 0; r < 4; r++) {
      float e = 0.125f * s[r];
      float mn = fmaxf(mr[r], e);
      lr[r] = lr[r] * __expf(mr[r] - mn) + __expf(e - mn);
      mr[r] = mn;
    }
  }
#pragma unroll
  for (int mask = 1; mask < 16; mask <<= 1)
#pragma unroll
    for (int r = 0; r < 4; r++) {
      float om = __shfl_xor(mr[r], mask);
      float ol = __shfl_xor(lr[r], mask);
      float mn = fmaxf(mr[r], om);
      lr[r] = lr[r] * __expf(mr[r] - mn) + ol * __expf(om - mn);
      mr[r] = mn;
    }
  if (fr == 0) {
#pragma unroll
    for (int r = 0; r < 4; r++) {
      int row = i0 + fk * 4 + r;
      mArr[(size_t)b * NTOK + row] = mr[r];
      rlArr[(size_t)b * NTOK + row] = 1.0f / lr[r];
    }
  }
}

// ---- K3: PV. out[b][c][i] = sum_j P[i][j]*V[c][j] + xs + xt
__global__ void __launch_bounds__(512)
k_pv(const unsigned short* __restrict__ Q, const unsigned short* __restrict__ Kt,
     const unsigned short* __restrict__ V, const float* __restrict__ mArr,
     const float* __restrict__ rlArr, const float* __restrict__ xs,
     const float* __restrict__ xt, float* __restrict__ out) {
  __shared__ __align__(16) unsigned short P_lds[64 * 64];
  int b = blockIdx.y;
  int i0 = blockIdx.x * 64;
  int tid = threadIdx.x;
  int w = tid >> 6, l = tid & 63, fr = l & 15, fk = l >> 4;
  int jcol = w >> 1;       // 0..3 : which 16-col group of P this wave computes
  int isb = (w & 1) * 2;   // istrip base 0 or 2
  int c0 = w * 64;         // channel slice for phase B
  bf16x8 qa[2][2];
  float mi[2][4], rli[2][4];
#pragma unroll
  for (int s = 0; s < 2; s++) {
    int istrip = isb + s;
    const unsigned short* qb = Q + ((size_t)b * NTOK + i0 + istrip * 16 + fr) * CQD + fk * 8;
    qa[s][0] = load_frag(qb);
    qa[s][1] = load_frag(qb + 32);
#pragma unroll
    for (int r = 0; r < 4; r++) {
      int row = i0 + istrip * 16 + fk * 4 + r;
      mi[s][r] = mArr[(size_t)b * NTOK + row];
      rli[s][r] = rlArr[(size_t)b * NTOK + row];
    }
  }
  f32x4 acc[4][4] = {};  // [nstrip(i)][cfrag]
  const unsigned short* vbase = V + ((size_t)b * CH + c0 + fr) * NTOK + fk * 8;
  const unsigned short* kbase = Kt + ((size_t)b * NTOK + jcol * 16 + fr) * CQD + fk * 8;
  for (int j = 0; j < NTOK; j += 64) {
    // phase A: compute P tile (64 x 64), 2 frags per wave
    bf16x8 kb0 = load_frag(kbase + (size_t)j * CQD);
    bf16x8 kb1 = load_frag(kbase + (size_t)j * CQD + 32);
#pragma unroll
    for (int s = 0; s < 2; s++) {
      f32x4 sf = {};
      sf = __builtin_amdgcn_mfma_f32_16x16x32_bf16(qa[s][0], kb0, sf, 0, 0, 0);
      sf = __builtin_amdgcn_mfma_f32_16x16x32_bf16(qa[s][1], kb1, sf, 0, 0, 0);
      int istrip = isb + s;
#pragma unroll
      for (int r = 0; r < 4; r++) {
        float e = 0.125f * sf[r];
        float p = __expf(e - mi[s][r]) * rli[s][r];
        int row = istrip * 16 + fk * 4 + r;
        int colb = (jcol * 16 + fr) * 2;
        int byteoff = row * 128 + (colb ^ ((row & 7) << 4));
        *reinterpret_cast<unsigned short*>(reinterpret_cast<char*>(P_lds) + byteoff) = f2bf(p);
      }
    }
    __syncthreads();
    // phase B: acc += P(64x64) @ V^T-slice(64x64)
#pragma unroll
    for (int jk = 0; jk < 2; jk++) {
      bf16x8 pa[4];
#pragma unroll
      for (int ns = 0; ns < 4; ns++) {
        int row = ns * 16 + fr;
        int byteoff = row * 128 + ((jk * 64 + fk * 16) ^ ((row & 7) << 4));
        pa[ns] = __builtin_bit_cast(
            bf16x8, *reinterpret_cast<const u32x4*>(reinterpret_cast<const char*>(P_lds) + byteoff));
      }
#pragma unroll
      for (int cf = 0; cf < 4; cf++) {
        bf16x8 vb = load_frag(vbase + (size_t)cf * 16 * NTOK + j + jk * 32);
#pragma unroll
        for (int ns = 0; ns < 4; ns++)
          acc[ns][cf] = __builtin_amdgcn_mfma_f32_16x16x32_bf16(pa[ns], vb, acc[ns][cf], 0, 0, 0);
      }
    }
    __syncthreads();
  }
#pragma unroll
  for (int ns = 0; ns < 4; ns++)
#pragma unroll
    for (int cf = 0; cf < 4; cf++) {
      int c = c0 + cf * 16 + fr;
      int nb = i0 + ns * 16 + fk * 4;
      size_t idx = ((size_t)b * CH + c) * NTOK + nb;
      f32x4 r1 = *reinterpret_cast<const f32x4*>(xs + idx);
      f32x4 r2 = *reinterpret_cast<const f32x4*>(xt + idx);
      f32x4 o = acc[ns][cf] + r1 + r2;
      *reinterpret_cast<f32x4*>(out + idx) = o;
    }
}

extern "C" void kernel_launch(void* const* d_in, const int* in_sizes, int n_in,
                              void* d_out, int out_size, void* d_ws, size_t ws_size,
                              hipStream_t stream) {
  const float* xs  = (const float*)d_in[0];
  const float* xt  = (const float*)d_in[1];
  const float* Wq  = (const float*)d_in[2];
  const float* bq  = (const float*)d_in[3];
  const float* Wk  = (const float*)d_in[4];
  const float* bk  = (const float*)d_in[5];
  const float* Wvs = (const float*)d_in[6];
  const float* bvs = (const float*)d_in[7];
  const float* Wvt = (const float*)d_in[8];
  const float* bvt = (const float*)d_in[9];
  float* out = (float*)d_out;

  char* ws = (char*)d_ws;
  size_t off = 0;
  unsigned short* xT = (unsigned short*)(ws + off); off += (size_t)NBATCH * NTOK * 1024 * 2;
  unsigned short* wq = (unsigned short*)(ws + off); off += (size_t)64 * 512 * 2;
  unsigned short* wk = (unsigned short*)(ws + off); off += (size_t)64 * 512 * 2;
  unsigned short* wv = (unsigned short*)(ws + off); off += (size_t)512 * 1024 * 2;
  unsigned short* Qb  = (unsigned short*)(ws + off); off += (size_t)NBATCH * NTOK * CQD * 2;
  unsigned short* Ktb = (unsigned short*)(ws + off); off += (size_t)NBATCH * NTOK * CQD * 2;
  unsigned short* Vb  = (unsigned short*)(ws + off); off += (size_t)NBATCH * CH * NTOK * 2;
  float* mArr  = (float*)(ws + off); off += (size_t)NBATCH * NTOK * 4;
  float* rlArr = (float*)(ws + off); off += (size_t)NBATCH * NTOK * 4;
  if (ws_size < off) return;  // insufficient scratch: fail safely

  k_transpose<<<dim3(NTOK / 64, 16, NBATCH), 256, 0, stream>>>(xs, xt, xT);
  k_weights<<<dim3(2304), 256, 0, stream>>>(Wq, Wk, Wvs, Wvt, wq, wk, wv);
  k_proj<<<dim3(NTOK / 256, 1, NBATCH), 256, 0, stream>>>(xT, wq, bq, nullptr, Qb, 512, 0, 0);
  k_proj<<<dim3(NTOK / 256, 1, NBATCH), 256, 0, stream>>>(xT, wk, bk, nullptr, Ktb, 512, 512, 0);
  k_proj<<<dim3(NTOK / 256, 8, NBATCH), 256, 0, stream>>>(xT, wv, bvs, bvt, Vb, 1024, 0, 1);
  k_stats<<<dim3(NTOK / 64, NBATCH), 256, 0, stream>>>(Qb, Ktb, mArr, rlArr);
  k_pv<<<dim3(NTOK / 64, NBATCH), 512, 0, stream>>>(Qb, Ktb, Vb, mArr, rlArr, xs, xt, out);
}

// Round 3
// 392.421 us; speedup vs baseline: 1.0553x; 1.0553x over previous
//
#include <hip/hip_runtime.h>
#include <hip/hip_bf16.h>
#include <math.h>

#define NTOK 4096
#define CH 512
#define CQD 64
#define NBATCH 4
#define JB 128

typedef __bf16 bf16x8 __attribute__((ext_vector_type(8)));
typedef float f32x4 __attribute__((ext_vector_type(4)));
typedef unsigned int u32x4 __attribute__((ext_vector_type(4)));
typedef unsigned short u16x4 __attribute__((ext_vector_type(4)));

__device__ __forceinline__ unsigned short f2bf(float f) {
  unsigned int u = __builtin_bit_cast(unsigned int, f);
  unsigned int r = (u + 0x7FFFu + ((u >> 16) & 1u)) >> 16;
  return (unsigned short)r;
}

__device__ __forceinline__ bf16x8 load_frag(const unsigned short* p) {
  u32x4 v = *reinterpret_cast<const u32x4*>(p);
  return __builtin_bit_cast(bf16x8, v);
}

// ---- K0a: transpose + convert x -> xT bf16 (B, N, 1024): [0..511]=xs, [512..1023]=xt
__global__ void k_transpose(const float* __restrict__ xs, const float* __restrict__ xt,
                            unsigned short* __restrict__ xT) {
  __shared__ unsigned short lds[64][66];
  int b = blockIdx.z;
  int n0 = blockIdx.x * 64;
  int c0 = blockIdx.y * 64;  // 0..1023
  const float* src = (c0 < CH) ? xs : xt;
  int cs0 = (c0 < CH) ? c0 : c0 - CH;
  int tid = threadIdx.x;
  int nn = tid & 63, cg = tid >> 6;
  const float* base = src + ((size_t)b * CH + cs0) * NTOK + n0;
  for (int cc = cg; cc < 64; cc += 4)
    lds[cc][nn] = f2bf(base[(size_t)cc * NTOK + nn]);
  __syncthreads();
  int cw = tid & 63, ng = tid >> 6;
  unsigned short* dst = xT + ((size_t)b * NTOK + n0) * 1024 + c0 + cw;
  for (int n2 = ng; n2 < 64; n2 += 4)
    dst[(size_t)n2 * 1024] = lds[cw][n2];
}

// ---- K0b: weights f32 -> bf16 (Wq, Wk, Wv = [Wvs | Wvt])
__global__ void k_weights(const float* __restrict__ Wq, const float* __restrict__ Wk,
                          const float* __restrict__ Wvs, const float* __restrict__ Wvt,
                          unsigned short* __restrict__ wq, unsigned short* __restrict__ wk,
                          unsigned short* __restrict__ wv) {
  int t = blockIdx.x * 256 + threadIdx.x;
  if (t < 32768) {
    wq[t] = f2bf(Wq[t]);
  } else if (t < 65536) {
    int j = t - 32768;
    wk[j] = f2bf(Wk[j]);
  } else {
    int j = t - 65536;
    if (j < 512 * 1024) {
      int c = j >> 10, k = j & 1023;
      float v = (k < 512) ? Wvs[c * 512 + k] : Wvt[c * 512 + (k - 512)];
      wv[j] = f2bf(v);
    }
  }
}

// ---- K1: projection GEMM. D[n][m] = sum_k xT[b][n][koff+k] * W[m][k] (+bias)
// mode 0: out[b][n][m] (N x 64) scalar bf16 stores (for Q, Kt)
// mode 1: out[b][m][n] (C x N) packed 4-wide bf16 stores (for V)
__global__ void __launch_bounds__(256)
k_proj(const unsigned short* __restrict__ xT, const unsigned short* __restrict__ W,
       const float* __restrict__ bias1, const float* __restrict__ bias2,
       unsigned short* __restrict__ out, int Kdim, int koff, int mode) {
  int b = blockIdx.z;
  int n0 = blockIdx.x * 256;
  int m0 = blockIdx.y * 64;
  int tid = threadIdx.x;
  int w = tid >> 6, l = tid & 63;
  int fr = l & 15, fk = l >> 4;
  f32x4 acc[4][4] = {};  // [nstrip][mfrag]
  const unsigned short* xbase =
      xT + ((size_t)b * NTOK + n0 + w * 64 + fr) * 1024 + koff + fk * 8;
  const unsigned short* wbase = W + ((size_t)(m0 + fr)) * Kdim + fk * 8;
  for (int k = 0; k < Kdim; k += 32) {
    bf16x8 a[4], bb[4];
#pragma unroll
    for (int ns = 0; ns < 4; ns++) a[ns] = load_frag(xbase + (size_t)ns * 16 * 1024 + k);
#pragma unroll
    for (int mf = 0; mf < 4; mf++) bb[mf] = load_frag(wbase + (size_t)mf * 16 * Kdim + k);
#pragma unroll
    for (int ns = 0; ns < 4; ns++)
#pragma unroll
      for (int mf = 0; mf < 4; mf++)
        acc[ns][mf] = __builtin_amdgcn_mfma_f32_16x16x32_bf16(a[ns], bb[mf], acc[ns][mf], 0, 0, 0);
  }
  if (mode == 0) {
#pragma unroll
    for (int ns = 0; ns < 4; ns++)
#pragma unroll
      for (int mf = 0; mf < 4; mf++) {
        int m = m0 + mf * 16 + fr;
        float bv = bias1[m];
        int nb = n0 + w * 64 + ns * 16 + fk * 4;
#pragma unroll
        for (int r = 0; r < 4; r++)
          out[((size_t)b * NTOK + nb + r) * CQD + m] = f2bf(acc[ns][mf][r] + bv);
      }
  } else {
#pragma unroll
    for (int ns = 0; ns < 4; ns++)
#pragma unroll
      for (int mf = 0; mf < 4; mf++) {
        int c = m0 + mf * 16 + fr;
        float bv = bias1[c] + bias2[c];
        int nb = n0 + w * 64 + ns * 16 + fk * 4;
        u16x4 pk;
#pragma unroll
        for (int r = 0; r < 4; r++) pk[r] = f2bf(acc[ns][mf][r] + bv);
        *reinterpret_cast<u16x4*>(out + ((size_t)b * CH + c) * NTOK + nb) = pk;
      }
  }
}

// ---- K2: fused attention+PV. out[b][c][i] = (sum_j e^{E[i][j]-8} V[c][j]) / denom[i] + xs + xt
// Block: 64 i-rows x 256 channels (cg half). 4 waves; wave = 64 ch slice + its 32-j P slice.
// Phase A (swapped 16x16x32 MFMA: A=K so D rows are j): lane holds 4 consecutive j for one i
//   -> lane-local row-sum partials (denominator fused) + one u16x4 LDS store (XOR-swizzled).
// Phase B: acc += P(64x128) @ V^T with verified 16x16x32 pattern (P from LDS, V from L2).
__global__ void __launch_bounds__(256)
k_pv(const unsigned short* __restrict__ Q, const unsigned short* __restrict__ Kt,
     const unsigned short* __restrict__ V, const float* __restrict__ xs,
     const float* __restrict__ xt, float* __restrict__ out) {
  __shared__ __align__(16) unsigned short P_lds[64 * JB];  // [i 64][j 128] bf16, 256B rows
  __shared__ float denom_lds[4][64];
  __shared__ float rden_lds[64];
  int b = blockIdx.z;
  int i0 = blockIdx.x * 64;
  int cg = blockIdx.y;  // 0..1
  int tid = threadIdx.x;
  int w = tid >> 6;   // wave 0..3
  int l = tid & 63;
  int fr = l & 15, fk = l >> 4;
  int c0 = cg * 256 + w * 64;

  // Q frags (B operand of S^T): col=lane&15 -> i = i0+f*16+fr, k = kk*32 + fk*8 + e
  bf16x8 qf[4][2];
#pragma unroll
  for (int f = 0; f < 4; f++) {
    const unsigned short* qb = Q + ((size_t)b * NTOK + i0 + f * 16 + fr) * CQD + fk * 8;
    qf[f][0] = load_frag(qb);
    qf[f][1] = load_frag(qb + 32);
  }
  float dsum[4] = {0.f, 0.f, 0.f, 0.f};  // per-lane: i = f*16 + fr
  f32x4 acc[4][4] = {};                   // [is][cf]

  // K rows (A operand): row=lane&15 -> j, k = fk*8 (+32 chained)
  const unsigned short* kbase = Kt + ((size_t)b * NTOK + w * 32 + fr) * CQD + fk * 8;
  // V rows (B operand of PV): col=lane&15 -> c, j-k = fk*8 (+32 chained)
  const unsigned short* vbase = V + ((size_t)b * CH + c0 + fr) * NTOK + fk * 8;

  for (int j0 = 0; j0 < NTOK; j0 += JB) {
    // ---- phase A: P rows i0..i0+63, wave w covers j in [j0+w*32, j0+w*32+32)
#pragma unroll
    for (int jf = 0; jf < 2; jf++) {
      bf16x8 kf0 = load_frag(kbase + (size_t)(j0 + jf * 16) * CQD);
      bf16x8 kf1 = load_frag(kbase + (size_t)(j0 + jf * 16) * CQD + 32);
#pragma unroll
      for (int f = 0; f < 4; f++) {
        f32x4 s = {};
        s = __builtin_amdgcn_mfma_f32_16x16x32_bf16(kf0, qf[f][0], s, 0, 0, 0);
        s = __builtin_amdgcn_mfma_f32_16x16x32_bf16(kf1, qf[f][1], s, 0, 0, 0);
        // lane: i = i0 + f*16 + fr (D col), j = j0 + w*32 + jf*16 + fk*4 + r (D row)
        u16x4 pk;
#pragma unroll
        for (int r = 0; r < 4; r++) {
          float p = __expf(0.125f * s[r] - 8.0f);
          dsum[f] += p;
          pk[r] = f2bf(p);
        }
        int prow = f * 16 + fr;
        int col = w * 64 + jf * 32 + fk * 8;  // byte col = 2*(j-rel)
        *reinterpret_cast<u16x4*>(reinterpret_cast<char*>(P_lds) + prow * (JB * 2) +
                                  (col ^ ((prow & 7) << 4))) = pk;
      }
    }
    __syncthreads();
    // ---- phase B: acc[is][cf] += P @ V^T (verified R1 pattern, row stride 256B)
#pragma unroll
    for (int js = 0; js < 4; js++) {
      bf16x8 pa[4];
#pragma unroll
      for (int is = 0; is < 4; is++) {
        int prow = is * 16 + fr;
        int byteoff = prow * (JB * 2) + ((js * 64 + fk * 16) ^ ((prow & 7) << 4));
        pa[is] = __builtin_bit_cast(
            bf16x8, *reinterpret_cast<const u32x4*>(reinterpret_cast<const char*>(P_lds) + byteoff));
      }
#pragma unroll
      for (int cf = 0; cf < 4; cf++) {
        bf16x8 vf = load_frag(vbase + (size_t)cf * 16 * NTOK + j0 + js * 32);
#pragma unroll
        for (int is = 0; is < 4; is++)
          acc[is][cf] = __builtin_amdgcn_mfma_f32_16x16x32_bf16(pa[is], vf, acc[is][cf], 0, 0, 0);
      }
    }
    __syncthreads();
  }

  // ---- denominator: combine fk groups (lanes l, l^16, l^32, l^48 share i), then waves
#pragma unroll
  for (int f = 0; f < 4; f++) {
    float v = dsum[f];
    v += __shfl_xor(v, 16);
    v += __shfl_xor(v, 32);
    if (l < 16) denom_lds[w][f * 16 + l] = v;
  }
  __syncthreads();
  if (tid < 64) {
    float d = denom_lds[0][tid] + denom_lds[1][tid] + denom_lds[2][tid] + denom_lds[3][tid];
    rden_lds[tid] = 1.0f / d;
  }
  __syncthreads();

  // ---- epilogue: out = acc * rden + xs + xt (verified R1 pattern)
#pragma unroll
  for (int is = 0; is < 4; is++)
#pragma unroll
    for (int cf = 0; cf < 4; cf++) {
      int c = c0 + cf * 16 + fr;
      size_t base = ((size_t)b * CH + c) * NTOK + i0 + is * 16 + fk * 4;
      f32x4 r1 = *reinterpret_cast<const f32x4*>(xs + base);
      f32x4 r2 = *reinterpret_cast<const f32x4*>(xt + base);
      f32x4 o;
#pragma unroll
      for (int r = 0; r < 4; r++)
        o[r] = acc[is][cf][r] * rden_lds[is * 16 + fk * 4 + r] + r1[r] + r2[r];
      *reinterpret_cast<f32x4*>(out + base) = o;
    }
}

extern "C" void kernel_launch(void* const* d_in, const int* in_sizes, int n_in,
                              void* d_out, int out_size, void* d_ws, size_t ws_size,
                              hipStream_t stream) {
  const float* xs  = (const float*)d_in[0];
  const float* xt  = (const float*)d_in[1];
  const float* Wq  = (const float*)d_in[2];
  const float* bq  = (const float*)d_in[3];
  const float* Wk  = (const float*)d_in[4];
  const float* bk  = (const float*)d_in[5];
  const float* Wvs = (const float*)d_in[6];
  const float* bvs = (const float*)d_in[7];
  const float* Wvt = (const float*)d_in[8];
  const float* bvt = (const float*)d_in[9];
  float* out = (float*)d_out;

  char* ws = (char*)d_ws;
  size_t off = 0;
  unsigned short* xT = (unsigned short*)(ws + off); off += (size_t)NBATCH * NTOK * 1024 * 2;
  unsigned short* wq = (unsigned short*)(ws + off); off += (size_t)64 * 512 * 2;
  unsigned short* wk = (unsigned short*)(ws + off); off += (size_t)64 * 512 * 2;
  unsigned short* wv = (unsigned short*)(ws + off); off += (size_t)512 * 1024 * 2;
  unsigned short* Qb  = (unsigned short*)(ws + off); off += (size_t)NBATCH * NTOK * CQD * 2;
  unsigned short* Ktb = (unsigned short*)(ws + off); off += (size_t)NBATCH * NTOK * CQD * 2;
  unsigned short* Vb  = (unsigned short*)(ws + off); off += (size_t)NBATCH * CH * NTOK * 2;
  if (ws_size < off) return;  // insufficient scratch: fail safely

  k_transpose<<<dim3(NTOK / 64, 16, NBATCH), 256, 0, stream>>>(xs, xt, xT);
  k_weights<<<dim3(2304), 256, 0, stream>>>(Wq, Wk, Wvs, Wvt, wq, wk, wv);
  k_proj<<<dim3(NTOK / 256, 1, NBATCH), 256, 0, stream>>>(xT, wq, bq, nullptr, Qb, 512, 0, 0);
  k_proj<<<dim3(NTOK / 256, 1, NBATCH), 256, 0, stream>>>(xT, wk, bk, nullptr, Ktb, 512, 512, 0);
  k_proj<<<dim3(NTOK / 256, 8, NBATCH), 256, 0, stream>>>(xT, wv, bvs, bvt, Vb, 1024, 0, 1);
  k_pv<<<dim3(NTOK / 64, 2, NBATCH), 256, 0, stream>>>(Qb, Ktb, Vb, xs, xt, out);
}

// Round 4
// 297.394 us; speedup vs baseline: 1.3925x; 1.3195x over previous
//
#include <hip/hip_runtime.h>
#include <hip/hip_bf16.h>
#include <math.h>

#define NTOK 4096
#define CH 512
#define CQD 64
#define NBATCH 4
#define JB 128

typedef __bf16 bf16x8 __attribute__((ext_vector_type(8)));
typedef float f32x4 __attribute__((ext_vector_type(4)));
typedef unsigned int u32x4 __attribute__((ext_vector_type(4)));
typedef unsigned short u16x4 __attribute__((ext_vector_type(4)));

__device__ __forceinline__ unsigned short f2bf(float f) {
  unsigned int u = __builtin_bit_cast(unsigned int, f);
  unsigned int r = (u + 0x7FFFu + ((u >> 16) & 1u)) >> 16;
  return (unsigned short)r;
}

__device__ __forceinline__ bf16x8 load_frag(const unsigned short* p) {
  u32x4 v = *reinterpret_cast<const u32x4*>(p);
  return __builtin_bit_cast(bf16x8, v);
}

// ---- K0a: transpose + convert x -> xT bf16 (B, N, 1024): [0..511]=xs, [512..1023]=xt
__global__ void k_transpose(const float* __restrict__ xs, const float* __restrict__ xt,
                            unsigned short* __restrict__ xT) {
  __shared__ unsigned short lds[64][66];
  int b = blockIdx.z;
  int n0 = blockIdx.x * 64;
  int c0 = blockIdx.y * 64;  // 0..1023
  const float* src = (c0 < CH) ? xs : xt;
  int cs0 = (c0 < CH) ? c0 : c0 - CH;
  int tid = threadIdx.x;
  int nn = tid & 63, cg = tid >> 6;
  const float* base = src + ((size_t)b * CH + cs0) * NTOK + n0;
  for (int cc = cg; cc < 64; cc += 4)
    lds[cc][nn] = f2bf(base[(size_t)cc * NTOK + nn]);
  __syncthreads();
  int cw = tid & 63, ng = tid >> 6;
  unsigned short* dst = xT + ((size_t)b * NTOK + n0) * 1024 + c0 + cw;
  for (int n2 = ng; n2 < 64; n2 += 4)
    dst[(size_t)n2 * 1024] = lds[cw][n2];
}

// ---- K0b: weights f32 -> bf16 (Wq, Wk, Wv = [Wvs | Wvt])
__global__ void k_weights(const float* __restrict__ Wq, const float* __restrict__ Wk,
                          const float* __restrict__ Wvs, const float* __restrict__ Wvt,
                          unsigned short* __restrict__ wq, unsigned short* __restrict__ wk,
                          unsigned short* __restrict__ wv) {
  int t = blockIdx.x * 256 + threadIdx.x;
  if (t < 32768) {
    wq[t] = f2bf(Wq[t]);
  } else if (t < 65536) {
    int j = t - 32768;
    wk[j] = f2bf(Wk[j]);
  } else {
    int j = t - 65536;
    if (j < 512 * 1024) {
      int c = j >> 10, k = j & 1023;
      float v = (k < 512) ? Wvs[c * 512 + k] : Wvt[c * 512 + (k - 512)];
      wv[j] = f2bf(v);
    }
  }
}

// ---- K1: projection GEMM. D[n][m] = sum_k xT[b][n][koff+k] * W[m][k] (+bias)
// mode 0: out[b][n][m] (N x 64) scalar bf16 stores (for Q, Kt)
// mode 1: out[b][m][n] (C x N) packed 4-wide bf16 stores (for V)
__global__ void __launch_bounds__(256)
k_proj(const unsigned short* __restrict__ xT, const unsigned short* __restrict__ W,
       const float* __restrict__ bias1, const float* __restrict__ bias2,
       unsigned short* __restrict__ out, int Kdim, int koff, int mode) {
  int b = blockIdx.z;
  int n0 = blockIdx.x * 256;
  int m0 = blockIdx.y * 64;
  int tid = threadIdx.x;
  int w = tid >> 6, l = tid & 63;
  int fr = l & 15, fk = l >> 4;
  f32x4 acc[4][4] = {};  // [nstrip][mfrag]
  const unsigned short* xbase =
      xT + ((size_t)b * NTOK + n0 + w * 64 + fr) * 1024 + koff + fk * 8;
  const unsigned short* wbase = W + ((size_t)(m0 + fr)) * Kdim + fk * 8;
  for (int k = 0; k < Kdim; k += 32) {
    bf16x8 a[4], bb[4];
#pragma unroll
    for (int ns = 0; ns < 4; ns++) a[ns] = load_frag(xbase + (size_t)ns * 16 * 1024 + k);
#pragma unroll
    for (int mf = 0; mf < 4; mf++) bb[mf] = load_frag(wbase + (size_t)mf * 16 * Kdim + k);
#pragma unroll
    for (int ns = 0; ns < 4; ns++)
#pragma unroll
      for (int mf = 0; mf < 4; mf++)
        acc[ns][mf] = __builtin_amdgcn_mfma_f32_16x16x32_bf16(a[ns], bb[mf], acc[ns][mf], 0, 0, 0);
  }
  if (mode == 0) {
#pragma unroll
    for (int ns = 0; ns < 4; ns++)
#pragma unroll
      for (int mf = 0; mf < 4; mf++) {
        int m = m0 + mf * 16 + fr;
        float bv = bias1[m];
        int nb = n0 + w * 64 + ns * 16 + fk * 4;
#pragma unroll
        for (int r = 0; r < 4; r++)
          out[((size_t)b * NTOK + nb + r) * CQD + m] = f2bf(acc[ns][mf][r] + bv);
      }
  } else {
#pragma unroll
    for (int ns = 0; ns < 4; ns++)
#pragma unroll
      for (int mf = 0; mf < 4; mf++) {
        int c = m0 + mf * 16 + fr;
        float bv = bias1[c] + bias2[c];
        int nb = n0 + w * 64 + ns * 16 + fk * 4;
        u16x4 pk;
#pragma unroll
        for (int r = 0; r < 4; r++) pk[r] = f2bf(acc[ns][mf][r] + bv);
        *reinterpret_cast<u16x4*>(out + ((size_t)b * CH + c) * NTOK + nb) = pk;
      }
  }
}

// ---- K2: fused attention+PV, software-pipelined.
// Block: 64 i-rows x ALL 512 channels, 8 waves (wave = 64 ch + 16-j slice of P).
// Double-buffered P LDS; ONE barrier per 128-j tile: iter t computes P(t+1) into
// buf[nxt] (swapped 16x16x32 QK, exp, fused denom partials) while PV-ing tile t
// from buf[cur]. All layouts are the R1/R3 hardware-verified 16x16x32 mappings.
__global__ void __launch_bounds__(512, 2)
k_pv(const unsigned short* __restrict__ Q, const unsigned short* __restrict__ Kt,
     const unsigned short* __restrict__ V, const float* __restrict__ xs,
     const float* __restrict__ xt, float* __restrict__ out) {
  __shared__ __align__(16) unsigned short P_lds[2][64 * JB];  // 2 x 16KB, 256B rows, XOR-swizzled
  __shared__ float denom_lds[8][64];
  __shared__ float rden_lds[64];
  int b = blockIdx.y;
  int i0 = blockIdx.x * 64;
  int tid = threadIdx.x;
  int w = tid >> 6;   // wave 0..7
  int l = tid & 63;
  int fr = l & 15, fk = l >> 4;
  int c0 = w * 64;

  // Q frags (B operand of S^T): col=lane&15 -> i = i0+f*16+fr, k = fk*8+e (+32 chained)
  bf16x8 qf[4][2];
#pragma unroll
  for (int f = 0; f < 4; f++) {
    const unsigned short* qb = Q + ((size_t)b * NTOK + i0 + f * 16 + fr) * CQD + fk * 8;
    qf[f][0] = load_frag(qb);
    qf[f][1] = load_frag(qb + 32);
  }
  float dsum[4] = {0.f, 0.f, 0.f, 0.f};  // per-lane partial, i = f*16 + fr
  f32x4 acc[4][4] = {};                   // [is][cf]

  // K rows (A operand of S^T): row=lane&15 -> j = jn + w*16 + fr
  const unsigned short* kbase = Kt + ((size_t)b * NTOK + w * 16 + fr) * CQD + fk * 8;
  // V rows (B operand of PV): col=lane&15 -> c = c0+cf*16+fr
  const unsigned short* vbase = V + ((size_t)b * CH + c0 + fr) * NTOK + fk * 8;

  // phase A: P rows i0..i0+63 for j-tile starting at jn, into P_lds[buf]
  auto phaseA = [&](int jn, int buf) {
    bf16x8 kf0 = load_frag(kbase + (size_t)jn * CQD);
    bf16x8 kf1 = load_frag(kbase + (size_t)jn * CQD + 32);
    char* pb = reinterpret_cast<char*>(P_lds[buf]);
#pragma unroll
    for (int f = 0; f < 4; f++) {
      f32x4 s = {};
      s = __builtin_amdgcn_mfma_f32_16x16x32_bf16(kf0, qf[f][0], s, 0, 0, 0);
      s = __builtin_amdgcn_mfma_f32_16x16x32_bf16(kf1, qf[f][1], s, 0, 0, 0);
      // lane: i = i0+f*16+fr (D col), j = jn + w*16 + fk*4 + r (D row)
      u16x4 pk;
#pragma unroll
      for (int r = 0; r < 4; r++) {
        float p = __expf(0.125f * s[r] - 8.0f);
        dsum[f] += p;
        pk[r] = f2bf(p);
      }
      int prow = f * 16 + fr;
      int col = w * 32 + fk * 8;  // byte col = 2*(j - jn)
      *reinterpret_cast<u16x4*>(pb + prow * (JB * 2) + (col ^ ((prow & 7) << 4))) = pk;
    }
  };

  phaseA(0, 0);
  __syncthreads();

  for (int t = 0; t < NTOK / JB; t++) {
    int cur = t & 1;
    int jc = t * JB;
    if (t < NTOK / JB - 1) phaseA(jc + JB, cur ^ 1);
    // ---- phase B: acc[is][cf] += P(64x128, buf cur) @ V^T
    const char* pb = reinterpret_cast<const char*>(P_lds[cur]);
#pragma unroll
    for (int js = 0; js < 4; js++) {
      bf16x8 pa[4];
#pragma unroll
      for (int is = 0; is < 4; is++) {
        int prow = is * 16 + fr;
        int byteoff = prow * (JB * 2) + ((js * 64 + fk * 16) ^ ((prow & 7) << 4));
        pa[is] = __builtin_bit_cast(bf16x8,
                                    *reinterpret_cast<const u32x4*>(pb + byteoff));
      }
#pragma unroll
      for (int cf = 0; cf < 4; cf++) {
        bf16x8 vf = load_frag(vbase + (size_t)cf * 16 * NTOK + jc + js * 32);
#pragma unroll
        for (int is = 0; is < 4; is++)
          acc[is][cf] = __builtin_amdgcn_mfma_f32_16x16x32_bf16(pa[is], vf, acc[is][cf], 0, 0, 0);
      }
    }
    __syncthreads();
  }

  // ---- denominator: combine fk groups (lanes l, l^16, l^32, l^48 share i), then waves
#pragma unroll
  for (int f = 0; f < 4; f++) {
    float v = dsum[f];
    v += __shfl_xor(v, 16);
    v += __shfl_xor(v, 32);
    if (l < 16) denom_lds[w][f * 16 + l] = v;
  }
  __syncthreads();
  if (tid < 64) {
    float d = 0.f;
#pragma unroll
    for (int ww = 0; ww < 8; ww++) d += denom_lds[ww][tid];
    rden_lds[tid] = 1.0f / d;
  }
  __syncthreads();

  // ---- epilogue: out = acc * rden + xs + xt
#pragma unroll
  for (int is = 0; is < 4; is++)
#pragma unroll
    for (int cf = 0; cf < 4; cf++) {
      int c = c0 + cf * 16 + fr;
      size_t base = ((size_t)b * CH + c) * NTOK + i0 + is * 16 + fk * 4;
      f32x4 r1 = *reinterpret_cast<const f32x4*>(xs + base);
      f32x4 r2 = *reinterpret_cast<const f32x4*>(xt + base);
      f32x4 o;
#pragma unroll
      for (int r = 0; r < 4; r++)
        o[r] = acc[is][cf][r] * rden_lds[is * 16 + fk * 4 + r] + r1[r] + r2[r];
      *reinterpret_cast<f32x4*>(out + base) = o;
    }
}

extern "C" void kernel_launch(void* const* d_in, const int* in_sizes, int n_in,
                              void* d_out, int out_size, void* d_ws, size_t ws_size,
                              hipStream_t stream) {
  const float* xs  = (const float*)d_in[0];
  const float* xt  = (const float*)d_in[1];
  const float* Wq  = (const float*)d_in[2];
  const float* bq  = (const float*)d_in[3];
  const float* Wk  = (const float*)d_in[4];
  const float* bk  = (const float*)d_in[5];
  const float* Wvs = (const float*)d_in[6];
  const float* bvs = (const float*)d_in[7];
  const float* Wvt = (const float*)d_in[8];
  const float* bvt = (const float*)d_in[9];
  float* out = (float*)d_out;

  char* ws = (char*)d_ws;
  size_t off = 0;
  unsigned short* xT = (unsigned short*)(ws + off); off += (size_t)NBATCH * NTOK * 1024 * 2;
  unsigned short* wq = (unsigned short*)(ws + off); off += (size_t)64 * 512 * 2;
  unsigned short* wk = (unsigned short*)(ws + off); off += (size_t)64 * 512 * 2;
  unsigned short* wv = (unsigned short*)(ws + off); off += (size_t)512 * 1024 * 2;
  unsigned short* Qb  = (unsigned short*)(ws + off); off += (size_t)NBATCH * NTOK * CQD * 2;
  unsigned short* Ktb = (unsigned short*)(ws + off); off += (size_t)NBATCH * NTOK * CQD * 2;
  unsigned short* Vb  = (unsigned short*)(ws + off); off += (size_t)NBATCH * CH * NTOK * 2;
  if (ws_size < off) return;  // insufficient scratch: fail safely

  k_transpose<<<dim3(NTOK / 64, 16, NBATCH), 256, 0, stream>>>(xs, xt, xT);
  k_weights<<<dim3(2304), 256, 0, stream>>>(Wq, Wk, Wvs, Wvt, wq, wk, wv);
  k_proj<<<dim3(NTOK / 256, 1, NBATCH), 256, 0, stream>>>(xT, wq, bq, nullptr, Qb, 512, 0, 0);
  k_proj<<<dim3(NTOK / 256, 1, NBATCH), 256, 0, stream>>>(xT, wk, bk, nullptr, Ktb, 512, 512, 0);
  k_proj<<<dim3(NTOK / 256, 8, NBATCH), 256, 0, stream>>>(xT, wv, bvs, bvt, Vb, 1024, 0, 1);
  k_pv<<<dim3(NTOK / 64, NBATCH), 512, 0, stream>>>(Qb, Ktb, Vb, xs, xt, out);
}

// Round 5
// 285.738 us; speedup vs baseline: 1.4494x; 1.0408x over previous
//
#include <hip/hip_runtime.h>
#include <hip/hip_bf16.h>
#include <math.h>

#define NTOK 4096
#define CH 512
#define CQD 64
#define NBATCH 4
#define JB 128

typedef __bf16 bf16x8 __attribute__((ext_vector_type(8)));
typedef float f32x4 __attribute__((ext_vector_type(4)));
typedef unsigned int u32x4 __attribute__((ext_vector_type(4)));
typedef unsigned short u16x4 __attribute__((ext_vector_type(4)));

__device__ __forceinline__ unsigned short f2bf(float f) {
  unsigned int u = __builtin_bit_cast(unsigned int, f);
  unsigned int r = (u + 0x7FFFu + ((u >> 16) & 1u)) >> 16;
  return (unsigned short)r;
}

__device__ __forceinline__ bf16x8 load_frag(const unsigned short* p) {
  u32x4 v = *reinterpret_cast<const u32x4*>(p);
  return __builtin_bit_cast(bf16x8, v);
}

// ---- K0a: transpose + convert x -> xT bf16 (B, N, 1024): [0..511]=xs, [512..1023]=xt
__global__ void k_transpose(const float* __restrict__ xs, const float* __restrict__ xt,
                            unsigned short* __restrict__ xT) {
  __shared__ unsigned short lds[64][66];
  int b = blockIdx.z;
  int n0 = blockIdx.x * 64;
  int c0 = blockIdx.y * 64;  // 0..1023
  const float* src = (c0 < CH) ? xs : xt;
  int cs0 = (c0 < CH) ? c0 : c0 - CH;
  int tid = threadIdx.x;
  int nn = tid & 63, cg = tid >> 6;
  const float* base = src + ((size_t)b * CH + cs0) * NTOK + n0;
  for (int cc = cg; cc < 64; cc += 4)
    lds[cc][nn] = f2bf(base[(size_t)cc * NTOK + nn]);
  __syncthreads();
  int cw = tid & 63, ng = tid >> 6;
  unsigned short* dst = xT + ((size_t)b * NTOK + n0) * 1024 + c0 + cw;
  for (int n2 = ng; n2 < 64; n2 += 4)
    dst[(size_t)n2 * 1024] = lds[cw][n2];
}

// ---- K0b: weights f32 -> bf16 (Wq, Wk, Wv = [Wvs | Wvt])
__global__ void k_weights(const float* __restrict__ Wq, const float* __restrict__ Wk,
                          const float* __restrict__ Wvs, const float* __restrict__ Wvt,
                          unsigned short* __restrict__ wq, unsigned short* __restrict__ wk,
                          unsigned short* __restrict__ wv) {
  int t = blockIdx.x * 256 + threadIdx.x;
  if (t < 32768) {
    wq[t] = f2bf(Wq[t]);
  } else if (t < 65536) {
    int j = t - 32768;
    wk[j] = f2bf(Wk[j]);
  } else {
    int j = t - 65536;
    if (j < 512 * 1024) {
      int c = j >> 10, k = j & 1023;
      float v = (k < 512) ? Wvs[c * 512 + k] : Wvt[c * 512 + (k - 512)];
      wv[j] = f2bf(v);
    }
  }
}

// ---- K1: projection GEMM. D[n][m] = sum_k xT[b][n][koff+k] * W[m][k] (+bias)
// mode 0: out[b][n][m] (N x 64) scalar bf16 stores (for Q, Kt)
// mode 1: out[b][m][n] (C x N) packed 4-wide bf16 stores (for V)
__global__ void __launch_bounds__(256)
k_proj(const unsigned short* __restrict__ xT, const unsigned short* __restrict__ W,
       const float* __restrict__ bias1, const float* __restrict__ bias2,
       unsigned short* __restrict__ out, int Kdim, int koff, int mode) {
  int b = blockIdx.z;
  int n0 = blockIdx.x * 256;
  int m0 = blockIdx.y * 64;
  int tid = threadIdx.x;
  int w = tid >> 6, l = tid & 63;
  int fr = l & 15, fk = l >> 4;
  f32x4 acc[4][4] = {};  // [nstrip][mfrag]
  const unsigned short* xbase =
      xT + ((size_t)b * NTOK + n0 + w * 64 + fr) * 1024 + koff + fk * 8;
  const unsigned short* wbase = W + ((size_t)(m0 + fr)) * Kdim + fk * 8;
  for (int k = 0; k < Kdim; k += 32) {
    bf16x8 a[4], bb[4];
#pragma unroll
    for (int ns = 0; ns < 4; ns++) a[ns] = load_frag(xbase + (size_t)ns * 16 * 1024 + k);
#pragma unroll
    for (int mf = 0; mf < 4; mf++) bb[mf] = load_frag(wbase + (size_t)mf * 16 * Kdim + k);
#pragma unroll
    for (int ns = 0; ns < 4; ns++)
#pragma unroll
      for (int mf = 0; mf < 4; mf++)
        acc[ns][mf] = __builtin_amdgcn_mfma_f32_16x16x32_bf16(a[ns], bb[mf], acc[ns][mf], 0, 0, 0);
  }
  if (mode == 0) {
#pragma unroll
    for (int ns = 0; ns < 4; ns++)
#pragma unroll
      for (int mf = 0; mf < 4; mf++) {
        int m = m0 + mf * 16 + fr;
        float bv = bias1[m];
        int nb = n0 + w * 64 + ns * 16 + fk * 4;
#pragma unroll
        for (int r = 0; r < 4; r++)
          out[((size_t)b * NTOK + nb + r) * CQD + m] = f2bf(acc[ns][mf][r] + bv);
      }
  } else {
#pragma unroll
    for (int ns = 0; ns < 4; ns++)
#pragma unroll
      for (int mf = 0; mf < 4; mf++) {
        int c = m0 + mf * 16 + fr;
        float bv = bias1[c] + bias2[c];
        int nb = n0 + w * 64 + ns * 16 + fk * 4;
        u16x4 pk;
#pragma unroll
        for (int r = 0; r < 4; r++) pk[r] = f2bf(acc[ns][mf][r] + bv);
        *reinterpret_cast<u16x4*>(out + ((size_t)b * CH + c) * NTOK + nb) = pk;
      }
  }
}

// ---- K2: fused attention+PV, software-pipelined with register prefetch (T14).
// Block: 64 i-rows x ALL 512 channels, 8 waves (wave = 64 ch + 16-j slice of P).
// Unroll-2 over j-tiles (static P0/P1). Per half-iter:
//   phaseA(kf -> Pnxt) ; loadK(+2 tiles ahead) ; phaseB(Pcur, vf) [setprio] ;
//   barrier ; loadV(next tile)   <- V in flight across next phaseA (~500cyc).
__global__ void __launch_bounds__(512, 2)
k_pv(const unsigned short* __restrict__ Q, const unsigned short* __restrict__ Kt,
     const unsigned short* __restrict__ V, const float* __restrict__ xs,
     const float* __restrict__ xt, float* __restrict__ out) {
  __shared__ __align__(16) unsigned short P0_lds[64 * JB];  // 16KB, 256B rows, XOR-swizzled
  __shared__ __align__(16) unsigned short P1_lds[64 * JB];
  __shared__ float denom_lds[8][64];
  __shared__ float rden_lds[64];
  int b = blockIdx.y;
  int i0 = blockIdx.x * 64;
  int tid = threadIdx.x;
  int w = tid >> 6;   // wave 0..7
  int l = tid & 63;
  int fr = l & 15, fk = l >> 4;
  int c0 = w * 64;

  // Q frags (B operand of S^T): col=lane&15 -> i = i0+f*16+fr, k = fk*8+e (+32 chained)
  bf16x8 qf[4][2];
#pragma unroll
  for (int f = 0; f < 4; f++) {
    const unsigned short* qb = Q + ((size_t)b * NTOK + i0 + f * 16 + fr) * CQD + fk * 8;
    qf[f][0] = load_frag(qb);
    qf[f][1] = load_frag(qb + 32);
  }
  float dsum[4] = {0.f, 0.f, 0.f, 0.f};  // per-lane partial, i = f*16 + fr
  f32x4 acc[4][4] = {};                   // [is][cf]

  // K rows (A operand of S^T): row=lane&15 -> j = jn + w*16 + fr
  const unsigned short* kbase = Kt + ((size_t)b * NTOK + w * 16 + fr) * CQD + fk * 8;
  // V rows (B operand of PV): col=lane&15 -> c = c0+cf*16+fr
  const unsigned short* vbase = V + ((size_t)b * CH + c0 + fr) * NTOK + fk * 8;

  bf16x8 kf0, kf1;     // K frags for the next phaseA tile
  bf16x8 vf[16];       // V frags for the current phaseB tile ([cf][js] flattened)

  auto loadK = [&](int jn) {
    kf0 = load_frag(kbase + (size_t)jn * CQD);
    kf1 = load_frag(kbase + (size_t)jn * CQD + 32);
  };
  auto loadV = [&](int jc) {
#pragma unroll
    for (int cf = 0; cf < 4; cf++)
#pragma unroll
      for (int js = 0; js < 4; js++)
        vf[cf * 4 + js] = load_frag(vbase + (size_t)cf * 16 * NTOK + jc + js * 32);
  };
  // phase A: P rows i0..i0+63 for j-tile at jn, into pb (uses kf0/kf1)
  auto phaseA = [&](int jn, unsigned short* plds) {
    char* pb = reinterpret_cast<char*>(plds);
#pragma unroll
    for (int f = 0; f < 4; f++) {
      f32x4 s = {};
      s = __builtin_amdgcn_mfma_f32_16x16x32_bf16(kf0, qf[f][0], s, 0, 0, 0);
      s = __builtin_amdgcn_mfma_f32_16x16x32_bf16(kf1, qf[f][1], s, 0, 0, 0);
      u16x4 pk;
#pragma unroll
      for (int r = 0; r < 4; r++) {
        float p = __expf(0.125f * s[r] - 8.0f);
        dsum[f] += p;
        pk[r] = f2bf(p);
      }
      int prow = f * 16 + fr;
      int col = w * 32 + fk * 8;  // byte col = 2*(j - jn)
      *reinterpret_cast<u16x4*>(pb + prow * (JB * 2) + (col ^ ((prow & 7) << 4))) = pk;
    }
  };
  // phase B: acc += P(64x128) @ V^T, P from plds, V from vf registers
  auto phaseB = [&](const unsigned short* plds) {
    const char* pb = reinterpret_cast<const char*>(plds);
    __builtin_amdgcn_s_setprio(1);
#pragma unroll
    for (int js = 0; js < 4; js++) {
      bf16x8 pa[4];
#pragma unroll
      for (int is = 0; is < 4; is++) {
        int prow = is * 16 + fr;
        int byteoff = prow * (JB * 2) + ((js * 64 + fk * 16) ^ ((prow & 7) << 4));
        pa[is] = __builtin_bit_cast(bf16x8, *reinterpret_cast<const u32x4*>(pb + byteoff));
      }
#pragma unroll
      for (int cf = 0; cf < 4; cf++) {
#pragma unroll
        for (int is = 0; is < 4; is++)
          acc[is][cf] =
              __builtin_amdgcn_mfma_f32_16x16x32_bf16(pa[is], vf[cf * 4 + js], acc[is][cf], 0, 0, 0);
      }
    }
    __builtin_amdgcn_s_setprio(0);
  };

  constexpr int NT = NTOK / JB;  // 32
  // ---- prologue: vf=V(0), P0=P(0), kf=K(1)
  loadK(0);
  loadV(0);
  phaseA(0, P0_lds);
  loadK(JB);
  __syncthreads();

  for (int t = 0; t < NT; t += 2) {
    // half 1: invariant P0=P(t), vf=V(t), kf=K(t+1)
    phaseA((t + 1) * JB, P1_lds);
    if (t + 2 < NT) loadK((t + 2) * JB);
    phaseB(P0_lds);
    __syncthreads();
    loadV((t + 1) * JB);
    // half 2: P1=P(t+1), vf<-V(t+1) in flight, kf=K(t+2)
    if (t + 2 < NT) {
      phaseA((t + 2) * JB, P0_lds);
      if (t + 3 < NT) loadK((t + 3) * JB);
    }
    phaseB(P1_lds);
    __syncthreads();
    if (t + 2 < NT) loadV((t + 2) * JB);
  }

  // ---- denominator: combine fk groups (lanes l, l^16, l^32, l^48 share i), then waves
#pragma unroll
  for (int f = 0; f < 4; f++) {
    float v = dsum[f];
    v += __shfl_xor(v, 16);
    v += __shfl_xor(v, 32);
    if (l < 16) denom_lds[w][f * 16 + l] = v;
  }
  __syncthreads();
  if (tid < 64) {
    float d = 0.f;
#pragma unroll
    for (int ww = 0; ww < 8; ww++) d += denom_lds[ww][tid];
    rden_lds[tid] = 1.0f / d;
  }
  __syncthreads();

  // ---- epilogue: out = acc * rden + xs + xt
#pragma unroll
  for (int is = 0; is < 4; is++)
#pragma unroll
    for (int cf = 0; cf < 4; cf++) {
      int c = c0 + cf * 16 + fr;
      size_t base = ((size_t)b * CH + c) * NTOK + i0 + is * 16 + fk * 4;
      f32x4 r1 = *reinterpret_cast<const f32x4*>(xs + base);
      f32x4 r2 = *reinterpret_cast<const f32x4*>(xt + base);
      f32x4 o;
#pragma unroll
      for (int r = 0; r < 4; r++)
        o[r] = acc[is][cf][r] * rden_lds[is * 16 + fk * 4 + r] + r1[r] + r2[r];
      *reinterpret_cast<f32x4*>(out + base) = o;
    }
}

extern "C" void kernel_launch(void* const* d_in, const int* in_sizes, int n_in,
                              void* d_out, int out_size, void* d_ws, size_t ws_size,
                              hipStream_t stream) {
  const float* xs  = (const float*)d_in[0];
  const float* xt  = (const float*)d_in[1];
  const float* Wq  = (const float*)d_in[2];
  const float* bq  = (const float*)d_in[3];
  const float* Wk  = (const float*)d_in[4];
  const float* bk  = (const float*)d_in[5];
  const float* Wvs = (const float*)d_in[6];
  const float* bvs = (const float*)d_in[7];
  const float* Wvt = (const float*)d_in[8];
  const float* bvt = (const float*)d_in[9];
  float* out = (float*)d_out;

  char* ws = (char*)d_ws;
  size_t off = 0;
  unsigned short* xT = (unsigned short*)(ws + off); off += (size_t)NBATCH * NTOK * 1024 * 2;
  unsigned short* wq = (unsigned short*)(ws + off); off += (size_t)64 * 512 * 2;
  unsigned short* wk = (unsigned short*)(ws + off); off += (size_t)64 * 512 * 2;
  unsigned short* wv = (unsigned short*)(ws + off); off += (size_t)512 * 1024 * 2;
  unsigned short* Qb  = (unsigned short*)(ws + off); off += (size_t)NBATCH * NTOK * CQD * 2;
  unsigned short* Ktb = (unsigned short*)(ws + off); off += (size_t)NBATCH * NTOK * CQD * 2;
  unsigned short* Vb  = (unsigned short*)(ws + off); off += (size_t)NBATCH * CH * NTOK * 2;
  if (ws_size < off) return;  // insufficient scratch: fail safely

  k_transpose<<<dim3(NTOK / 64, 16, NBATCH), 256, 0, stream>>>(xs, xt, xT);
  k_weights<<<dim3(2304), 256, 0, stream>>>(Wq, Wk, Wvs, Wvt, wq, wk, wv);
  k_proj<<<dim3(NTOK / 256, 1, NBATCH), 256, 0, stream>>>(xT, wq, bq, nullptr, Qb, 512, 0, 0);
  k_proj<<<dim3(NTOK / 256, 1, NBATCH), 256, 0, stream>>>(xT, wk, bk, nullptr, Ktb, 512, 512, 0);
  k_proj<<<dim3(NTOK / 256, 8, NBATCH), 256, 0, stream>>>(xT, wv, bvs, bvt, Vb, 1024, 0, 1);
  k_pv<<<dim3(NTOK / 64, NBATCH), 512, 0, stream>>>(Qb, Ktb, Vb, xs, xt, out);
}